// Round 2
// baseline (528.870 us; speedup 1.0000x reference)
//
#include <hip/hip_runtime.h>
#include <hip/hip_bf16.h>

typedef __bf16 bf16x8 __attribute__((ext_vector_type(8)));
typedef __bf16 bf16x4 __attribute__((ext_vector_type(4)));
typedef float  f32x4  __attribute__((ext_vector_type(4)));

#define MIN_VALUE (-1.7014118346046923e38f)

// async global->LDS direct copy, 16 B per lane. LDS dest = wave-uniform base +
// lane*16; we pass each lane's own consistent pointer (lane0's == base).
__device__ __forceinline__ void async_load16(const __bf16* g, __bf16* l) {
    __builtin_amdgcn_global_load_lds(
        (const __attribute__((address_space(1))) uint32_t*)(uintptr_t)g,
        (__attribute__((address_space(3))) uint32_t*)(uint32_t)(uintptr_t)l,
        16, 0, 0);
}

// -------------------------------------------------------- fused prep:
//   blocks [0,4096)        : x -> bf16
//   blocks [4096,5120)     : Wo -> bf16 (natural [n][k])
//   blocks [5120,8192)     : transpose+split Wq/Wk/Wv -> [3072][1024] hi/lo
__global__ __launch_bounds__(256) void prep_kernel(
    const float* __restrict__ x, const float* __restrict__ Wq,
    const float* __restrict__ Wk, const float* __restrict__ Wv,
    const float* __restrict__ Wo,
    __bf16* __restrict__ xh, __bf16* __restrict__ wh, __bf16* __restrict__ wl,
    __bf16* __restrict__ wob) {
    __shared__ float t[32][33];
    const int bid = blockIdx.x;
    const int tid = threadIdx.x;
    if (bid < 4096) {
        int i = (bid * 256 + tid) * 4;
        float4 v = *(const float4*)(x + i);
        float vv[4] = {v.x, v.y, v.z, v.w};
        bf16x4 h;
        for (int e = 0; e < 4; ++e) h[e] = (__bf16)vv[e];
        *(bf16x4*)(xh + i) = h;
    } else if (bid < 5120) {
        int i = ((bid - 4096) * 256 + tid) * 4;
        float4 v = *(const float4*)(Wo + i);
        float vv[4] = {v.x, v.y, v.z, v.w};
        bf16x4 h;
        for (int e = 0; e < 4; ++e) h[e] = (__bf16)vv[e];
        *(bf16x4*)(wob + i) = h;
    } else {
        int b3 = bid - 5120;
        int bx = b3 & 31, by = (b3 >> 5) & 1, z = b3 >> 6;
        int sel = z >> 4, h = z & 15;
        const float* W = (sel == 0) ? Wq : (sel == 1) ? Wk : Wv;
        int i0 = bx * 32, d0 = by * 32;
        int tx = tid & 31, ty = tid >> 5;
        for (int it = 0; it < 4; ++it) {
            int r = ty + it * 8;
            t[r][tx] = W[(size_t)(h * 1024 + i0 + r) * 64 + d0 + tx];
        }
        __syncthreads();
        for (int it = 0; it < 4; ++it) {
            int r = ty + it * 8;
            float v = t[tx][r];
            size_t o = (size_t)(sel * 1024 + h * 64 + d0 + r) * 1024 + i0 + tx;
            __bf16 hi = (__bf16)v;
            wh[o] = hi;
            wl[o] = (__bf16)(v - (float)hi);
        }
    }
}

// ---------------------------------------------------------------- QKV GEMM (W hi/lo split)
// C[4096][3072] = xh[4096][1024] @ (Wh+Wl)^T ; lo-pass skipped for the v third
// (v precision governed by the loose out threshold).
// 1D grid + bijective XCD swizzle: each XCD sweeps all 32 m-tiles of 3 n-tiles
// (B panel stays L2-resident). v-third stores via LDS transpose -> bf16x8 coalesced.
__global__ __launch_bounds__(256) void qkv_gemm_kernel(
    const __bf16* __restrict__ xh,
    const __bf16* __restrict__ wh, const __bf16* __restrict__ wl,
    const float* __restrict__ bq, const float* __restrict__ bk, const float* __restrict__ bv,
    __bf16* __restrict__ qb, __bf16* __restrict__ kb, __bf16* __restrict__ vtb) {
    __shared__ __align__(16) char smem[33280];   // As(8K)+Bh(8K)+Bl(8K), aliased by T[128][130]
    __bf16* As = (__bf16*)smem;
    __bf16* Bh = As + 4096;
    __bf16* Bl = Bh + 4096;
    __bf16* T  = (__bf16*)smem;                  // 128*130 bf16 = 33280 B
    const int tid = threadIdx.x;
    const int bid = blockIdx.x;                  // 768 blocks
    const int nb = (bid & 7) * 96 + (bid >> 3);  // bijective XCD chunking
    const int m0 = (nb & 31) * 128;
    const int n0 = (nb >> 5) * 128;
    const int lane = tid & 63, w = tid >> 6;
    const int l15 = lane & 15, quad = lane >> 4;
    const int wm = (w & 1) * 64, wn = (w >> 1) * 64;
    const int r4 = lane >> 2;
    const int c8 = (lane & 3) * 8;
    const bool need_lo = (n0 < 2048);   // q,k blocks only

    f32x4 acc[4][4];
    for (int i = 0; i < 4; ++i)
        for (int j = 0; j < 4; ++j)
            for (int r = 0; r < 4; ++r) acc[i][j][r] = 0.0f;

    for (int kk = 0; kk < 1024; kk += 32) {
        __syncthreads();
        for (int half = 0; half < 2; ++half) {
            int row = w * 32 + half * 16 + r4;
            int lo = w * 1024 + half * 512 + lane * 8;
            async_load16(&xh[(size_t)(m0 + row) * 1024 + kk + c8], &As[lo]);
            async_load16(&wh[(size_t)(n0 + row) * 1024 + kk + c8], &Bh[lo]);
            if (need_lo)
                async_load16(&wl[(size_t)(n0 + row) * 1024 + kk + c8], &Bl[lo]);
        }
        __syncthreads();
        bf16x8 af[4], bhf[4], blf[4];
        for (int i = 0; i < 4; ++i)
            af[i] = *(const bf16x8*)&As[(wm + i * 16 + l15) * 32 + quad * 8];
        for (int j = 0; j < 4; ++j)
            bhf[j] = *(const bf16x8*)&Bh[(wn + j * 16 + l15) * 32 + quad * 8];
        if (need_lo)
            for (int j = 0; j < 4; ++j)
                blf[j] = *(const bf16x8*)&Bl[(wn + j * 16 + l15) * 32 + quad * 8];
        for (int i = 0; i < 4; ++i)
            for (int j = 0; j < 4; ++j)
                acc[i][j] = __builtin_amdgcn_mfma_f32_16x16x32_bf16(af[i], bhf[j], acc[i][j], 0, 0, 0);
        if (need_lo)
            for (int i = 0; i < 4; ++i)
                for (int j = 0; j < 4; ++j)
                    acc[i][j] = __builtin_amdgcn_mfma_f32_16x16x32_bf16(af[i], blf[j], acc[i][j], 0, 0, 0);
    }

    const int sel = n0 >> 10;
    const int bb = m0 >> 10;
    if (sel == 2) {
        // transpose tile in LDS, then coalesced bf16x8 stores of v^T rows
        __syncthreads();   // all waves done reading As/Bh before aliasing T
        for (int i = 0; i < 4; ++i)
            for (int j = 0; j < 4; ++j)
                for (int r = 0; r < 4; ++r) {
                    int nl = wn + j * 16 + l15;
                    int ml = wm + i * 16 + quad * 4 + r;
                    int nn = (n0 + nl) & 1023;
                    T[nl * 130 + ml] = (__bf16)(acc[i][j][r] + bv[nn]);
                }
        __syncthreads();
        for (int s = 0; s < 8; ++s) {
            int nl = s * 16 + (tid >> 4);
            int ml = (tid & 15) * 8;
            bf16x8 vv = *(const bf16x8*)&T[nl * 130 + ml];
            int n = n0 + nl;
            int h = (n & 1023) >> 6, d = n & 63;
            int ll = (m0 & 1023) + ml;
            *(bf16x8*)&vtb[(size_t)((bb * 16 + h) * 64 + d) * 1024 + ll] = vv;
        }
    } else {
        const float* bias = (sel == 0) ? bq : bk;
        __bf16* dst = (sel == 0) ? qb : kb;
        for (int i = 0; i < 4; ++i)
            for (int j = 0; j < 4; ++j)
                for (int r = 0; r < 4; ++r) {
                    int m = m0 + wm + i * 16 + quad * 4 + r;
                    int n = n0 + wn + j * 16 + l15;
                    int nn = n & 1023;
                    int h = nn >> 6, d = n & 63;
                    float v = acc[i][j][r] + bias[nn];
                    int ll = m & 1023;
                    dst[(size_t)((bb * 16 + h) * 1024 + ll) * 64 + d] = (__bf16)v;
                }
    }
}

// --------------------------------------- fused scores + mask + softmax + PV per 16-row tile
// S kept in registers (wave w owns cols [w*256, w*256+256)); cross-wave max/sum
// via tiny LDS buffers; bf16 P goes through LDS (PV operand transpose) and is
// ALSO the source for the normalized atten store (coalesced float4, 1 KB/instr).
// PV runs on UNnormalized P; 1/sum folded into the PV epilogue.
// 1D grid + bijective XCD swizzle: each XCD owns 8 whole (b,h) slices so K/V are
// fetched from LLC by exactly one XCD's L2 (was 8x duplicated).
__global__ __launch_bounds__(256, 4) void attn_kernel(
    const __bf16* __restrict__ qb, const __bf16* __restrict__ kb,
    const __bf16* __restrict__ vtb, const int* __restrict__ mask,
    float* __restrict__ atten, __bf16* __restrict__ value_bf) {
    __shared__ __bf16 P[16 * 1048];     // 32.75 KB, stride 1048 -> 2-way banks (free)
    __shared__ float red[2][4][16];     // [max/sum][wave][row]
    const int bid = blockIdx.x;                    // 4096 blocks
    const int nb = (bid & 7) * 512 + (bid >> 3);   // bijective XCD chunking
    const int m0 = (nb & 63) * 16;
    const int h = (nb >> 6) & 15, b = nb >> 10;
    const int bh = b * 16 + h;
    const int tid = threadIdx.x;
    const int lane = tid & 63, w = tid >> 6;
    const int l15 = lane & 15, quad = lane >> 4;

    // phase 1: scores in registers. C layout: row=quad*4+r, col=n0+l15.
    const __bf16* qbase = qb + (size_t)(bh * 1024 + m0 + l15) * 64 + quad * 8;
    bf16x8 a0 = *(const bf16x8*)(qbase);
    bf16x8 a1 = *(const bf16x8*)(qbase + 32);
    f32x4 s[16];
    for (int t = 0; t < 16; ++t) {
        int n0 = w * 256 + t * 16;
        const __bf16* kbase = kb + (size_t)(bh * 1024 + n0 + l15) * 64 + quad * 8;
        bf16x8 b0 = *(const bf16x8*)(kbase);
        bf16x8 b1 = *(const bf16x8*)(kbase + 32);
        f32x4 c = {0.f, 0.f, 0.f, 0.f};
        c = __builtin_amdgcn_mfma_f32_16x16x32_bf16(a0, b0, c, 0, 0, 0);
        c = __builtin_amdgcn_mfma_f32_16x16x32_bf16(a1, b1, c, 0, 0, 0);
        bool msk = (mask[b * 1024 + n0 + l15] == 0);
        for (int r = 0; r < 4; ++r) s[t][r] = msk ? MIN_VALUE : c[r] * 0.125f;
    }

    // phase 2a: row maxes (lane-local over t, shuffle over l15, LDS over waves)
    float mx[4];
    for (int r = 0; r < 4; ++r) {
        float m = s[0][r];
        for (int t = 1; t < 16; ++t) m = fmaxf(m, s[t][r]);
        for (int o = 1; o < 16; o <<= 1) m = fmaxf(m, __shfl_xor(m, o));
        mx[r] = m;
    }
    if (l15 == 0)
        for (int r = 0; r < 4; ++r) red[0][w][quad * 4 + r] = mx[r];
    __syncthreads();
    for (int r = 0; r < 4; ++r) {
        int row = quad * 4 + r;
        mx[r] = fmaxf(fmaxf(red[0][0][row], red[0][1][row]),
                      fmaxf(red[0][2][row], red[0][3][row]));
    }

    // phase 2b: exp (unnormalized), bf16 P to LDS, row sums
    float sum[4] = {0.f, 0.f, 0.f, 0.f};
    for (int t = 0; t < 16; ++t)
        for (int r = 0; r < 4; ++r) {
            float e = __expf(s[t][r] - mx[r]);
            sum[r] += e;
            P[(quad * 4 + r) * 1048 + w * 256 + t * 16 + l15] = (__bf16)e;
        }
    for (int r = 0; r < 4; ++r) {
        float sm = sum[r];
        for (int o = 1; o < 16; o <<= 1) sm += __shfl_xor(sm, o);
        sum[r] = sm;
    }
    if (l15 == 0)
        for (int r = 0; r < 4; ++r) red[1][w][quad * 4 + r] = sum[r];
    __syncthreads();   // covers P writes AND sum reduction
    float inv[4];
    for (int r = 0; r < 4; ++r) {
        int row = quad * 4 + r;
        inv[r] = 1.0f / (red[1][0][row] + red[1][1][row] +
                         red[1][2][row] + red[1][3][row]);
    }

    // phase 2c: coalesced normalized atten store. Wave w owns rows [w*4, w*4+4):
    // re-read bf16 P, scale, write float4 (64 lanes x 16 B = 1 KB contiguous).
    for (int r = 0; r < 4; ++r) {
        int row = w * 4 + r;
        float invr = 1.0f / (red[1][0][row] + red[1][1][row] +
                             red[1][2][row] + red[1][3][row]);
        float* out = atten + (size_t)(bh * 1024 + m0 + row) * 1024;
        for (int e = 0; e < 4; ++e) {
            bf16x4 pv = *(const bf16x4*)&P[row * 1048 + e * 256 + lane * 4];
            f32x4 o;
            for (int q2 = 0; q2 < 4; ++q2) o[q2] = (float)pv[q2] * invr;
            *(f32x4*)(out + e * 256 + lane * 4) = o;
        }
    }

    // phase 3: value = (P @ v) * inv ; wave w does d-cols [w*16, w*16+16)
    f32x4 acc = {0.f, 0.f, 0.f, 0.f};
    const __bf16* vbase = vtb + (size_t)(bh * 64 + w * 16 + l15) * 1024 + quad * 8;
    for (int kk = 0; kk < 1024; kk += 32) {
        bf16x8 af = *(const bf16x8*)&P[l15 * 1048 + kk + quad * 8];
        bf16x8 bf_ = *(const bf16x8*)(vbase + kk);
        acc = __builtin_amdgcn_mfma_f32_16x16x32_bf16(af, bf_, acc, 0, 0, 0);
    }
    for (int r = 0; r < 4; ++r) {
        int mrow = quad * 4 + r;
        value_bf[(size_t)(b * 1024 + m0 + mrow) * 1024 + h * 64 + w * 16 + l15] =
            (__bf16)(acc[r] * inv[r]);
    }
}

// ------------------------------- out-proj GEMM: pre = x + value @ Wo^T + bo  (plain bf16)
// 128x64 tiles, 512 blocks = 2 blocks/CU; 1D grid + bijective XCD swizzle
// (m fastest within XCD -> B panel L2-resident).
__global__ __launch_bounds__(256) void outproj_kernel(
    const __bf16* __restrict__ vb, const __bf16* __restrict__ wob,
    const float* __restrict__ x, const float* __restrict__ bo,
    float* __restrict__ pre) {
    __shared__ __bf16 As[128 * 32];
    __shared__ __bf16 Bs[64 * 32];
    const int tid = threadIdx.x;
    const int bid = blockIdx.x;                   // 512 blocks
    const int nb = (bid & 7) * 64 + (bid >> 3);   // bijective XCD chunking
    const int m0 = (nb & 31) * 128;
    const int n0 = (nb >> 5) * 64;
    const int lane = tid & 63, w = tid >> 6;
    const int l15 = lane & 15, quad = lane >> 4;
    const int wm = (w & 1) * 64, wn = (w >> 1) * 32;
    const int r4 = lane >> 2;
    const int c8 = (lane & 3) * 8;

    f32x4 acc[4][2];
    for (int i = 0; i < 4; ++i)
        for (int j = 0; j < 2; ++j)
            for (int r = 0; r < 4; ++r) acc[i][j][r] = 0.0f;

    for (int kk = 0; kk < 1024; kk += 32) {
        __syncthreads();
        for (int half = 0; half < 2; ++half) {
            int row = w * 32 + half * 16 + r4;
            int lo = w * 1024 + half * 512 + lane * 8;
            async_load16(&vb[(size_t)(m0 + row) * 1024 + kk + c8], &As[lo]);
        }
        {
            int row = w * 16 + r4;
            int lo = w * 512 + lane * 8;
            async_load16(&wob[(size_t)(n0 + row) * 1024 + kk + c8], &Bs[lo]);
        }
        __syncthreads();
        bf16x8 af[4], bfr[2];
        for (int i = 0; i < 4; ++i) af[i] = *(const bf16x8*)&As[(wm + i * 16 + l15) * 32 + quad * 8];
        for (int j = 0; j < 2; ++j) bfr[j] = *(const bf16x8*)&Bs[(wn + j * 16 + l15) * 32 + quad * 8];
        for (int i = 0; i < 4; ++i)
            for (int j = 0; j < 2; ++j)
                acc[i][j] = __builtin_amdgcn_mfma_f32_16x16x32_bf16(af[i], bfr[j], acc[i][j], 0, 0, 0);
    }

    for (int i = 0; i < 4; ++i)
        for (int j = 0; j < 2; ++j)
            for (int r = 0; r < 4; ++r) {
                int m = m0 + wm + i * 16 + quad * 4 + r;
                int n = n0 + wn + j * 16 + l15;
                pre[(size_t)m * 1024 + n] = acc[i][j][r] + x[(size_t)m * 1024 + n] + bo[n];
            }
}

// ---------------------------------------------------------------- LayerNorm (in place)
__global__ __launch_bounds__(256) void ln_kernel(float* __restrict__ buf,
                                                 const float* __restrict__ gamma,
                                                 const float* __restrict__ beta) {
    const int row = blockIdx.x;
    const int tid = threadIdx.x;
    const int lane = tid & 63, w = tid >> 6;
    __shared__ float red[8];
    float* rp = buf + (size_t)row * 1024;
    float loc[4];
    float s = 0.f, s2 = 0.f;
    for (int e = 0; e < 4; ++e) {
        loc[e] = rp[tid + e * 256];
        s += loc[e];
        s2 += loc[e] * loc[e];
    }
    for (int o = 32; o > 0; o >>= 1) {
        s += __shfl_xor(s, o);
        s2 += __shfl_xor(s2, o);
    }
    if (lane == 0) { red[w * 2] = s; red[w * 2 + 1] = s2; }
    __syncthreads();
    float ts = red[0] + red[2] + red[4] + red[6];
    float ts2 = red[1] + red[3] + red[5] + red[7];
    float mu = ts * (1.0f / 1024.0f);
    float var = ts2 * (1.0f / 1024.0f) - mu * mu;
    float sc = rsqrtf(var + 1e-5f);
    for (int e = 0; e < 4; ++e) {
        int c = tid + e * 256;
        rp[c] = (loc[e] - mu) * sc * gamma[c] + beta[c];
    }
}

extern "C" void kernel_launch(void* const* d_in, const int* in_sizes, int n_in,
                              void* d_out, int out_size, void* d_ws, size_t ws_size,
                              hipStream_t stream) {
    const float* x    = (const float*)d_in[0];
    const int*   mask = (const int*)d_in[1];
    const float* Wq   = (const float*)d_in[2];
    const float* bq   = (const float*)d_in[3];
    const float* Wk   = (const float*)d_in[4];
    const float* bk   = (const float*)d_in[5];
    const float* Wv   = (const float*)d_in[6];
    const float* bv   = (const float*)d_in[7];
    const float* Wo   = (const float*)d_in[8];
    const float* bo   = (const float*)d_in[9];
    const float* gamma= (const float*)d_in[10];
    const float* beta = (const float*)d_in[11];

    char* p = (char*)d_ws;
    __bf16* xh    = (__bf16*)p; p += (size_t)4194304 * 2;   // x bf16
    __bf16* wt_hi = (__bf16*)p; p += (size_t)3145728 * 2;   // Wqkv^T hi  [3072][1024]
    __bf16* wt_lo = (__bf16*)p; p += (size_t)3145728 * 2;   // Wqkv^T lo
    __bf16* wob   = (__bf16*)p; p += (size_t)1048576 * 2;   // Wo bf16 [n][k]
    __bf16* qb    = (__bf16*)p; p += (size_t)4194304 * 2;   // q [bh][l][64]
    __bf16* kb    = (__bf16*)p; p += (size_t)4194304 * 2;   // k [bh][l][64]
    __bf16* vtb   = (__bf16*)p; p += (size_t)4194304 * 2;   // v^T [bh][64][1024]
    __bf16* valb  = (__bf16*)p; p += (size_t)4194304 * 2;   // value [b*l][1024]

    float* outb  = (float*)d_out;            // [4096][1024] : pre, then LN in place
    float* atten = outb + 4194304;           // [64][1024][1024]

    prep_kernel<<<8192, 256, 0, stream>>>(x, Wq, Wk, Wv, Wo, xh, wt_hi, wt_lo, wob);
    qkv_gemm_kernel<<<768, 256, 0, stream>>>(xh, wt_hi, wt_lo, bq, bk, bv, qb, kb, vtb);
    attn_kernel<<<4096, 256, 0, stream>>>(qb, kb, vtb, mask, atten, valb);
    outproj_kernel<<<512, 256, 0, stream>>>(valb, wob, x, bo, outb);
    ln_kernel<<<4096, 256, 0, stream>>>(outb, gamma, beta);
}

// Round 4
// 509.782 us; speedup vs baseline: 1.0374x; 1.0374x over previous
//
#include <hip/hip_runtime.h>
#include <hip/hip_bf16.h>

typedef __bf16 bf16x8 __attribute__((ext_vector_type(8)));
typedef __bf16 bf16x4 __attribute__((ext_vector_type(4)));
typedef float  f32x4  __attribute__((ext_vector_type(4)));

#define MIN_VALUE (-1.7014118346046923e38f)

// async global->LDS direct copy, 16 B per lane. LDS dest = wave-uniform base +
// lane*16; we pass each lane's own consistent pointer (lane0's == base).
__device__ __forceinline__ void async_load16(const __bf16* g, __bf16* l) {
    __builtin_amdgcn_global_load_lds(
        (const __attribute__((address_space(1))) uint32_t*)(uintptr_t)g,
        (__attribute__((address_space(3))) uint32_t*)(uint32_t)(uintptr_t)l,
        16, 0, 0);
}

// -------------------------------------------------------- fused prep:
//   blocks [0,4096)        : x -> bf16
//   blocks [4096,5120)     : Wo -> bf16 (natural [n][k])
//   blocks [5120,8192)     : transpose+split Wq/Wk/Wv -> [3072][1024] hi/lo
__global__ __launch_bounds__(256) void prep_kernel(
    const float* __restrict__ x, const float* __restrict__ Wq,
    const float* __restrict__ Wk, const float* __restrict__ Wv,
    const float* __restrict__ Wo,
    __bf16* __restrict__ xh, __bf16* __restrict__ wh, __bf16* __restrict__ wl,
    __bf16* __restrict__ wob) {
    __shared__ float t[32][33];
    const int bid = blockIdx.x;
    const int tid = threadIdx.x;
    if (bid < 4096) {
        int i = (bid * 256 + tid) * 4;
        float4 v = *(const float4*)(x + i);
        float vv[4] = {v.x, v.y, v.z, v.w};
        bf16x4 h;
        for (int e = 0; e < 4; ++e) h[e] = (__bf16)vv[e];
        *(bf16x4*)(xh + i) = h;
    } else if (bid < 5120) {
        int i = ((bid - 4096) * 256 + tid) * 4;
        float4 v = *(const float4*)(Wo + i);
        float vv[4] = {v.x, v.y, v.z, v.w};
        bf16x4 h;
        for (int e = 0; e < 4; ++e) h[e] = (__bf16)vv[e];
        *(bf16x4*)(wob + i) = h;
    } else {
        int b3 = bid - 5120;
        int bx = b3 & 31, by = (b3 >> 5) & 1, z = b3 >> 6;
        int sel = z >> 4, h = z & 15;
        const float* W = (sel == 0) ? Wq : (sel == 1) ? Wk : Wv;
        int i0 = bx * 32, d0 = by * 32;
        int tx = tid & 31, ty = tid >> 5;
        for (int it = 0; it < 4; ++it) {
            int r = ty + it * 8;
            t[r][tx] = W[(size_t)(h * 1024 + i0 + r) * 64 + d0 + tx];
        }
        __syncthreads();
        for (int it = 0; it < 4; ++it) {
            int r = ty + it * 8;
            float v = t[tx][r];
            size_t o = (size_t)(sel * 1024 + h * 64 + d0 + r) * 1024 + i0 + tx;
            __bf16 hi = (__bf16)v;
            wh[o] = hi;
            wl[o] = (__bf16)(v - (float)hi);
        }
    }
}

// ---------------------------------------------------------------- QKV GEMM (W hi/lo split)
// C[4096][3072] = xh[4096][1024] @ (Wh+Wl)^T ; lo-pass skipped for the v third
// (v precision governed by the loose out threshold).
// v-third stores via LDS transpose -> bf16x8 coalesced (was 2-byte scatter at 2KB stride).
__global__ __launch_bounds__(256) void qkv_gemm_kernel(
    const __bf16* __restrict__ xh,
    const __bf16* __restrict__ wh, const __bf16* __restrict__ wl,
    const float* __restrict__ bq, const float* __restrict__ bk, const float* __restrict__ bv,
    __bf16* __restrict__ qb, __bf16* __restrict__ kb, __bf16* __restrict__ vtb) {
    __shared__ __align__(16) char smem[33280];   // As(8K)+Bh(8K)+Bl(8K), aliased by T[128][130]
    __bf16* As = (__bf16*)smem;
    __bf16* Bh = As + 4096;
    __bf16* Bl = Bh + 4096;
    __bf16* T  = (__bf16*)smem;                  // 128*130 bf16 = 33280 B
    const int tid = threadIdx.x;
    const int m0 = blockIdx.y * 128;
    const int n0 = blockIdx.x * 128;
    const int lane = tid & 63, w = tid >> 6;
    const int l15 = lane & 15, quad = lane >> 4;
    const int wm = (w & 1) * 64, wn = (w >> 1) * 64;
    const int r4 = lane >> 2;
    const int c8 = (lane & 3) * 8;
    const bool need_lo = (n0 < 2048);   // q,k blocks only

    f32x4 acc[4][4];
    for (int i = 0; i < 4; ++i)
        for (int j = 0; j < 4; ++j)
            for (int r = 0; r < 4; ++r) acc[i][j][r] = 0.0f;

    for (int kk = 0; kk < 1024; kk += 32) {
        __syncthreads();
        for (int half = 0; half < 2; ++half) {
            int row = w * 32 + half * 16 + r4;
            int lo = w * 1024 + half * 512 + lane * 8;
            async_load16(&xh[(size_t)(m0 + row) * 1024 + kk + c8], &As[lo]);
            async_load16(&wh[(size_t)(n0 + row) * 1024 + kk + c8], &Bh[lo]);
            if (need_lo)
                async_load16(&wl[(size_t)(n0 + row) * 1024 + kk + c8], &Bl[lo]);
        }
        __syncthreads();
        bf16x8 af[4], bhf[4], blf[4];
        for (int i = 0; i < 4; ++i)
            af[i] = *(const bf16x8*)&As[(wm + i * 16 + l15) * 32 + quad * 8];
        for (int j = 0; j < 4; ++j)
            bhf[j] = *(const bf16x8*)&Bh[(wn + j * 16 + l15) * 32 + quad * 8];
        if (need_lo)
            for (int j = 0; j < 4; ++j)
                blf[j] = *(const bf16x8*)&Bl[(wn + j * 16 + l15) * 32 + quad * 8];
        for (int i = 0; i < 4; ++i)
            for (int j = 0; j < 4; ++j)
                acc[i][j] = __builtin_amdgcn_mfma_f32_16x16x32_bf16(af[i], bhf[j], acc[i][j], 0, 0, 0);
        if (need_lo)
            for (int i = 0; i < 4; ++i)
                for (int j = 0; j < 4; ++j)
                    acc[i][j] = __builtin_amdgcn_mfma_f32_16x16x32_bf16(af[i], blf[j], acc[i][j], 0, 0, 0);
    }

    const int sel = n0 >> 10;
    const int bb = m0 >> 10;
    if (sel == 2) {
        // transpose tile in LDS, then coalesced bf16x8 stores of v^T rows
        __syncthreads();   // all waves done reading As/Bh/Bl before aliasing T
        for (int i = 0; i < 4; ++i)
            for (int j = 0; j < 4; ++j)
                for (int r = 0; r < 4; ++r) {
                    int nl = wn + j * 16 + l15;
                    int ml = wm + i * 16 + quad * 4 + r;
                    int nn = (n0 + nl) & 1023;
                    T[nl * 130 + ml] = (__bf16)(acc[i][j][r] + bv[nn]);
                }
        __syncthreads();
        for (int s = 0; s < 8; ++s) {
            int nl = s * 16 + (tid >> 4);
            int ml = (tid & 15) * 8;
            bf16x8 vv = *(const bf16x8*)&T[nl * 130 + ml];
            int n = n0 + nl;
            int h = (n & 1023) >> 6, d = n & 63;
            int ll = (m0 & 1023) + ml;
            *(bf16x8*)&vtb[(size_t)((bb * 16 + h) * 64 + d) * 1024 + ll] = vv;
        }
    } else {
        const float* bias = (sel == 0) ? bq : bk;
        __bf16* dst = (sel == 0) ? qb : kb;
        for (int i = 0; i < 4; ++i)
            for (int j = 0; j < 4; ++j)
                for (int r = 0; r < 4; ++r) {
                    int m = m0 + wm + i * 16 + quad * 4 + r;
                    int n = n0 + wn + j * 16 + l15;
                    int nn = n & 1023;
                    int h = nn >> 6, d = n & 63;
                    float v = acc[i][j][r] + bias[nn];
                    int ll = m & 1023;
                    dst[(size_t)((bb * 16 + h) * 1024 + ll) * 64 + d] = (__bf16)v;
                }
    }
}

// --------------------------------------- fused scores + mask + softmax + PV per 16-row tile
// S kept in registers (wave w owns cols [w*256, w*256+256)); cross-wave max/sum
// via tiny LDS buffers; bf16 P goes through LDS (PV operand transpose) and is
// ALSO the source for the normalized atten store (coalesced float4, 1 KB/instr).
// PV runs on UNnormalized P; 1/sum folded into the PV epilogue.
__global__ __launch_bounds__(256, 4) void attn_kernel(
    const __bf16* __restrict__ qb, const __bf16* __restrict__ kb,
    const __bf16* __restrict__ vtb, const int* __restrict__ mask,
    float* __restrict__ atten, __bf16* __restrict__ value_bf) {
    __shared__ __bf16 P[16 * 1048];     // 32.75 KB, stride 1048 -> 2-way banks (free)
    __shared__ float red[2][4][16];     // [max/sum][wave][row]
    const int m0 = blockIdx.x * 16;
    const int h = blockIdx.y, b = blockIdx.z;
    const int bh = b * 16 + h;
    const int tid = threadIdx.x;
    const int lane = tid & 63, w = tid >> 6;
    const int l15 = lane & 15, quad = lane >> 4;

    // phase 1: scores in registers. C layout: row=quad*4+r, col=n0+l15.
    const __bf16* qbase = qb + (size_t)(bh * 1024 + m0 + l15) * 64 + quad * 8;
    bf16x8 a0 = *(const bf16x8*)(qbase);
    bf16x8 a1 = *(const bf16x8*)(qbase + 32);
    f32x4 s[16];
    for (int t = 0; t < 16; ++t) {
        int n0 = w * 256 + t * 16;
        const __bf16* kbase = kb + (size_t)(bh * 1024 + n0 + l15) * 64 + quad * 8;
        bf16x8 b0 = *(const bf16x8*)(kbase);
        bf16x8 b1 = *(const bf16x8*)(kbase + 32);
        f32x4 c = {0.f, 0.f, 0.f, 0.f};
        c = __builtin_amdgcn_mfma_f32_16x16x32_bf16(a0, b0, c, 0, 0, 0);
        c = __builtin_amdgcn_mfma_f32_16x16x32_bf16(a1, b1, c, 0, 0, 0);
        bool msk = (mask[b * 1024 + n0 + l15] == 0);
        for (int r = 0; r < 4; ++r) s[t][r] = msk ? MIN_VALUE : c[r] * 0.125f;
    }

    // phase 2a: row maxes (lane-local over t, shuffle over l15, LDS over waves)
    float mx[4];
    for (int r = 0; r < 4; ++r) {
        float m = s[0][r];
        for (int t = 1; t < 16; ++t) m = fmaxf(m, s[t][r]);
        for (int o = 1; o < 16; o <<= 1) m = fmaxf(m, __shfl_xor(m, o));
        mx[r] = m;
    }
    if (l15 == 0)
        for (int r = 0; r < 4; ++r) red[0][w][quad * 4 + r] = mx[r];
    __syncthreads();
    for (int r = 0; r < 4; ++r) {
        int row = quad * 4 + r;
        mx[r] = fmaxf(fmaxf(red[0][0][row], red[0][1][row]),
                      fmaxf(red[0][2][row], red[0][3][row]));
    }

    // phase 2b: exp (unnormalized), bf16 P to LDS, row sums
    float sum[4] = {0.f, 0.f, 0.f, 0.f};
    for (int t = 0; t < 16; ++t)
        for (int r = 0; r < 4; ++r) {
            float e = __expf(s[t][r] - mx[r]);
            sum[r] += e;
            P[(quad * 4 + r) * 1048 + w * 256 + t * 16 + l15] = (__bf16)e;
        }
    for (int r = 0; r < 4; ++r) {
        float sm = sum[r];
        for (int o = 1; o < 16; o <<= 1) sm += __shfl_xor(sm, o);
        sum[r] = sm;
    }
    if (l15 == 0)
        for (int r = 0; r < 4; ++r) red[1][w][quad * 4 + r] = sum[r];
    __syncthreads();   // covers P writes AND sum reduction
    float inv[4];
    for (int r = 0; r < 4; ++r) {
        int row = quad * 4 + r;
        inv[r] = 1.0f / (red[1][0][row] + red[1][1][row] +
                         red[1][2][row] + red[1][3][row]);
    }

    // phase 2c: coalesced normalized atten store. Wave w owns rows [w*4, w*4+4):
    // re-read bf16 P, scale, write float4 (64 lanes x 16 B = 1 KB contiguous).
    for (int r = 0; r < 4; ++r) {
        int row = w * 4 + r;
        float invr = 1.0f / (red[1][0][row] + red[1][1][row] +
                             red[1][2][row] + red[1][3][row]);
        float* out = atten + (size_t)(bh * 1024 + m0 + row) * 1024;
        for (int e = 0; e < 4; ++e) {
            bf16x4 pv = *(const bf16x4*)&P[row * 1048 + e * 256 + lane * 4];
            f32x4 o;
            for (int q2 = 0; q2 < 4; ++q2) o[q2] = (float)pv[q2] * invr;
            *(f32x4*)(out + e * 256 + lane * 4) = o;
        }
    }

    // phase 3: value = (P @ v) * inv ; wave w does d-cols [w*16, w*16+16)
    f32x4 acc = {0.f, 0.f, 0.f, 0.f};
    const __bf16* vbase = vtb + (size_t)(bh * 64 + w * 16 + l15) * 1024 + quad * 8;
    for (int kk = 0; kk < 1024; kk += 32) {
        bf16x8 af = *(const bf16x8*)&P[l15 * 1048 + kk + quad * 8];
        bf16x8 bf_ = *(const bf16x8*)(vbase + kk);
        acc = __builtin_amdgcn_mfma_f32_16x16x32_bf16(af, bf_, acc, 0, 0, 0);
    }
    for (int r = 0; r < 4; ++r) {
        int mrow = quad * 4 + r;
        value_bf[(size_t)(b * 1024 + m0 + mrow) * 1024 + h * 64 + w * 16 + l15] =
            (__bf16)(acc[r] * inv[r]);
    }
}

// ------------------------------- out-proj GEMM: pre = x + value @ Wo^T + bo  (plain bf16)
// 128x64 tiles -> 512 blocks = 2 blocks/CU for cross-block latency hiding.
__global__ __launch_bounds__(256) void outproj_kernel(
    const __bf16* __restrict__ vb, const __bf16* __restrict__ wob,
    const float* __restrict__ x, const float* __restrict__ bo,
    float* __restrict__ pre) {
    __shared__ __bf16 As[128 * 32];
    __shared__ __bf16 Bs[64 * 32];
    const int tid = threadIdx.x;
    const int m0 = blockIdx.y * 128;
    const int n0 = blockIdx.x * 64;
    const int lane = tid & 63, w = tid >> 6;
    const int l15 = lane & 15, quad = lane >> 4;
    const int wm = (w & 1) * 64, wn = (w >> 1) * 32;
    const int r4 = lane >> 2;
    const int c8 = (lane & 3) * 8;

    f32x4 acc[4][2];
    for (int i = 0; i < 4; ++i)
        for (int j = 0; j < 2; ++j)
            for (int r = 0; r < 4; ++r) acc[i][j][r] = 0.0f;

    for (int kk = 0; kk < 1024; kk += 32) {
        __syncthreads();
        for (int half = 0; half < 2; ++half) {
            int row = w * 32 + half * 16 + r4;
            int lo = w * 1024 + half * 512 + lane * 8;
            async_load16(&vb[(size_t)(m0 + row) * 1024 + kk + c8], &As[lo]);
        }
        {
            int row = w * 16 + r4;
            int lo = w * 512 + lane * 8;
            async_load16(&wob[(size_t)(n0 + row) * 1024 + kk + c8], &Bs[lo]);
        }
        __syncthreads();
        bf16x8 af[4], bfr[2];
        for (int i = 0; i < 4; ++i) af[i] = *(const bf16x8*)&As[(wm + i * 16 + l15) * 32 + quad * 8];
        for (int j = 0; j < 2; ++j) bfr[j] = *(const bf16x8*)&Bs[(wn + j * 16 + l15) * 32 + quad * 8];
        for (int i = 0; i < 4; ++i)
            for (int j = 0; j < 2; ++j)
                acc[i][j] = __builtin_amdgcn_mfma_f32_16x16x32_bf16(af[i], bfr[j], acc[i][j], 0, 0, 0);
    }

    for (int i = 0; i < 4; ++i)
        for (int j = 0; j < 2; ++j)
            for (int r = 0; r < 4; ++r) {
                int m = m0 + wm + i * 16 + quad * 4 + r;
                int n = n0 + wn + j * 16 + l15;
                pre[(size_t)m * 1024 + n] = acc[i][j][r] + x[(size_t)m * 1024 + n] + bo[n];
            }
}

// ---------------------------------------------------------------- LayerNorm (in place)
__global__ __launch_bounds__(256) void ln_kernel(float* __restrict__ buf,
                                                 const float* __restrict__ gamma,
                                                 const float* __restrict__ beta) {
    const int row = blockIdx.x;
    const int tid = threadIdx.x;
    const int lane = tid & 63, w = tid >> 6;
    __shared__ float red[8];
    float* rp = buf + (size_t)row * 1024;
    float loc[4];
    float s = 0.f, s2 = 0.f;
    for (int e = 0; e < 4; ++e) {
        loc[e] = rp[tid + e * 256];
        s += loc[e];
        s2 += loc[e] * loc[e];
    }
    for (int o = 32; o > 0; o >>= 1) {
        s += __shfl_xor(s, o);
        s2 += __shfl_xor(s2, o);
    }
    if (lane == 0) { red[w * 2] = s; red[w * 2 + 1] = s2; }
    __syncthreads();
    float ts = red[0] + red[2] + red[4] + red[6];
    float ts2 = red[1] + red[3] + red[5] + red[7];
    float mu = ts * (1.0f / 1024.0f);
    float var = ts2 * (1.0f / 1024.0f) - mu * mu;
    float sc = rsqrtf(var + 1e-5f);
    for (int e = 0; e < 4; ++e) {
        int c = tid + e * 256;
        rp[c] = (loc[e] - mu) * sc * gamma[c] + beta[c];
    }
}

extern "C" void kernel_launch(void* const* d_in, const int* in_sizes, int n_in,
                              void* d_out, int out_size, void* d_ws, size_t ws_size,
                              hipStream_t stream) {
    const float* x    = (const float*)d_in[0];
    const int*   mask = (const int*)d_in[1];
    const float* Wq   = (const float*)d_in[2];
    const float* bq   = (const float*)d_in[3];
    const float* Wk   = (const float*)d_in[4];
    const float* bk   = (const float*)d_in[5];
    const float* Wv   = (const float*)d_in[6];
    const float* bv   = (const float*)d_in[7];
    const float* Wo   = (const float*)d_in[8];
    const float* bo   = (const float*)d_in[9];
    const float* gamma= (const float*)d_in[10];
    const float* beta = (const float*)d_in[11];

    char* p = (char*)d_ws;
    __bf16* xh    = (__bf16*)p; p += (size_t)4194304 * 2;   // x bf16
    __bf16* wt_hi = (__bf16*)p; p += (size_t)3145728 * 2;   // Wqkv^T hi  [3072][1024]
    __bf16* wt_lo = (__bf16*)p; p += (size_t)3145728 * 2;   // Wqkv^T lo
    __bf16* wob   = (__bf16*)p; p += (size_t)1048576 * 2;   // Wo bf16 [n][k]
    __bf16* qb    = (__bf16*)p; p += (size_t)4194304 * 2;   // q [bh][l][64]
    __bf16* kb    = (__bf16*)p; p += (size_t)4194304 * 2;   // k [bh][l][64]
    __bf16* vtb   = (__bf16*)p; p += (size_t)4194304 * 2;   // v^T [bh][64][1024]
    __bf16* valb  = (__bf16*)p; p += (size_t)4194304 * 2;   // value [b*l][1024]

    float* outb  = (float*)d_out;            // [4096][1024] : pre, then LN in place
    float* atten = outb + 4194304;           // [64][1024][1024]

    prep_kernel<<<8192, 256, 0, stream>>>(x, Wq, Wk, Wv, Wo, xh, wt_hi, wt_lo, wob);
    qkv_gemm_kernel<<<dim3(24, 32), 256, 0, stream>>>(xh, wt_hi, wt_lo, bq, bk, bv, qb, kb, vtb);
    attn_kernel<<<dim3(64, 16, 4), 256, 0, stream>>>(qb, kb, vtb, mask, atten, valb);
    outproj_kernel<<<dim3(16, 32), 256, 0, stream>>>(valb, wob, x, bo, outb);
    ln_kernel<<<4096, 256, 0, stream>>>(outb, gamma, beta);
}

// Round 5
// 494.452 us; speedup vs baseline: 1.0696x; 1.0310x over previous
//
#include <hip/hip_runtime.h>
#include <hip/hip_bf16.h>

typedef _Float16 f16;
typedef f16   f16x8 __attribute__((ext_vector_type(8)));
typedef f16   f16x4 __attribute__((ext_vector_type(4)));
typedef float f32x4 __attribute__((ext_vector_type(4)));

#define MIN_VALUE (-1.7014118346046923e38f)

// async global->LDS direct copy, 16 B per lane. LDS dest = wave-uniform base +
// lane*16; we pass each lane's own consistent pointer (lane0's == base).
__device__ __forceinline__ void async_load16(const f16* g, f16* l) {
    __builtin_amdgcn_global_load_lds(
        (const __attribute__((address_space(1))) uint32_t*)(uintptr_t)g,
        (__attribute__((address_space(3))) uint32_t*)(uint32_t)(uintptr_t)l,
        16, 0, 0);
}

// -------------------------------------------------------- fused prep (all fp16 now):
//   blocks [0,4096)        : x -> f16
//   blocks [4096,5120)     : Wo -> f16 (natural [n][k])
//   blocks [5120,8192)     : transpose Wq/Wk/Wv -> [3072][1024] f16 (no lo split)
__global__ __launch_bounds__(256) void prep_kernel(
    const float* __restrict__ x, const float* __restrict__ Wq,
    const float* __restrict__ Wk, const float* __restrict__ Wv,
    const float* __restrict__ Wo,
    f16* __restrict__ xh, f16* __restrict__ wt, f16* __restrict__ wob) {
    __shared__ float t[32][33];
    const int bid = blockIdx.x;
    const int tid = threadIdx.x;
    if (bid < 4096) {
        int i = (bid * 256 + tid) * 4;
        float4 v = *(const float4*)(x + i);
        float vv[4] = {v.x, v.y, v.z, v.w};
        f16x4 h;
        for (int e = 0; e < 4; ++e) h[e] = (f16)vv[e];
        *(f16x4*)(xh + i) = h;
    } else if (bid < 5120) {
        int i = ((bid - 4096) * 256 + tid) * 4;
        float4 v = *(const float4*)(Wo + i);
        float vv[4] = {v.x, v.y, v.z, v.w};
        f16x4 h;
        for (int e = 0; e < 4; ++e) h[e] = (f16)vv[e];
        *(f16x4*)(wob + i) = h;
    } else {
        int b3 = bid - 5120;
        int bx = b3 & 31, by = (b3 >> 5) & 1, z = b3 >> 6;
        int sel = z >> 4, h = z & 15;
        const float* W = (sel == 0) ? Wq : (sel == 1) ? Wk : Wv;
        int i0 = bx * 32, d0 = by * 32;
        int tx = tid & 31, ty = tid >> 5;
        for (int it = 0; it < 4; ++it) {
            int r = ty + it * 8;
            t[r][tx] = W[(size_t)(h * 1024 + i0 + r) * 64 + d0 + tx];
        }
        __syncthreads();
        for (int it = 0; it < 4; ++it) {
            int r = ty + it * 8;
            float v = t[tx][r];
            size_t o = (size_t)(sel * 1024 + h * 64 + d0 + r) * 1024 + i0 + tx;
            wt[o] = (f16)v;
        }
    }
}

// ---------------------------------------------------------------- QKV GEMM (single-pass fp16)
// C[4096][3072] = xh[4096][1024] @ wt^T. fp16 has 3 more mantissa bits than bf16
// at identical MFMA rate -> no hi/lo pass needed (score err ~2^-11*|s| ~ 4e-3).
// v-third stores via LDS transpose -> f16x8 coalesced.
__global__ __launch_bounds__(256) void qkv_gemm_kernel(
    const f16* __restrict__ xh, const f16* __restrict__ wt,
    const float* __restrict__ bq, const float* __restrict__ bk, const float* __restrict__ bv,
    f16* __restrict__ qb, f16* __restrict__ kb, f16* __restrict__ vtb) {
    __shared__ __align__(16) char smem[33280];   // As(8K)+Bs(8K); aliased by T[128][130] f16
    f16* As = (f16*)smem;
    f16* Bs = As + 4096;
    f16* T  = (f16*)smem;                        // 128*130 f16 = 33280 B
    const int tid = threadIdx.x;
    const int m0 = blockIdx.y * 128;
    const int n0 = blockIdx.x * 128;
    const int lane = tid & 63, w = tid >> 6;
    const int l15 = lane & 15, quad = lane >> 4;
    const int wm = (w & 1) * 64, wn = (w >> 1) * 64;
    const int r4 = lane >> 2;
    const int c8 = (lane & 3) * 8;

    f32x4 acc[4][4];
    for (int i = 0; i < 4; ++i)
        for (int j = 0; j < 4; ++j)
            for (int r = 0; r < 4; ++r) acc[i][j][r] = 0.0f;

    for (int kk = 0; kk < 1024; kk += 32) {
        __syncthreads();
        for (int half = 0; half < 2; ++half) {
            int row = w * 32 + half * 16 + r4;
            int lo = w * 1024 + half * 512 + lane * 8;
            async_load16(&xh[(size_t)(m0 + row) * 1024 + kk + c8], &As[lo]);
            async_load16(&wt[(size_t)(n0 + row) * 1024 + kk + c8], &Bs[lo]);
        }
        __syncthreads();
        f16x8 af[4], bf[4];
        for (int i = 0; i < 4; ++i)
            af[i] = *(const f16x8*)&As[(wm + i * 16 + l15) * 32 + quad * 8];
        for (int j = 0; j < 4; ++j)
            bf[j] = *(const f16x8*)&Bs[(wn + j * 16 + l15) * 32 + quad * 8];
        for (int i = 0; i < 4; ++i)
            for (int j = 0; j < 4; ++j)
                acc[i][j] = __builtin_amdgcn_mfma_f32_16x16x32_f16(af[i], bf[j], acc[i][j], 0, 0, 0);
    }

    const int sel = n0 >> 10;
    const int bb = m0 >> 10;
    if (sel == 2) {
        // transpose tile in LDS, then coalesced f16x8 stores of v^T rows
        __syncthreads();   // all waves done reading As/Bs before aliasing T
        for (int i = 0; i < 4; ++i)
            for (int j = 0; j < 4; ++j)
                for (int r = 0; r < 4; ++r) {
                    int nl = wn + j * 16 + l15;
                    int ml = wm + i * 16 + quad * 4 + r;
                    int nn = (n0 + nl) & 1023;
                    T[nl * 130 + ml] = (f16)(acc[i][j][r] + bv[nn]);
                }
        __syncthreads();
        for (int s = 0; s < 8; ++s) {
            int nl = s * 16 + (tid >> 4);
            int ml = (tid & 15) * 8;
            f16x8 vv = *(const f16x8*)&T[nl * 130 + ml];
            int n = n0 + nl;
            int h = (n & 1023) >> 6, d = n & 63;
            int ll = (m0 & 1023) + ml;
            *(f16x8*)&vtb[(size_t)((bb * 16 + h) * 64 + d) * 1024 + ll] = vv;
        }
    } else {
        const float* bias = (sel == 0) ? bq : bk;
        f16* dst = (sel == 0) ? qb : kb;
        for (int i = 0; i < 4; ++i)
            for (int j = 0; j < 4; ++j)
                for (int r = 0; r < 4; ++r) {
                    int m = m0 + wm + i * 16 + quad * 4 + r;
                    int n = n0 + wn + j * 16 + l15;
                    int nn = n & 1023;
                    int h = nn >> 6, d = n & 63;
                    float v = acc[i][j][r] + bias[nn];
                    int ll = m & 1023;
                    dst[(size_t)((bb * 16 + h) * 1024 + ll) * 64 + d] = (f16)v;
                }
    }
}

// --------------------------------------- fused scores + mask + softmax + PV per 16-row tile
// S kept in registers (wave w owns cols [w*256, w*256+256)); cross-wave max/sum
// via tiny LDS buffers; f16 P goes through LDS (PV operand transpose) and is
// ALSO the source for the normalized atten store (coalesced float4, 1 KB/instr).
// PV runs on UNnormalized P; 1/sum folded into the PV epilogue.
__global__ __launch_bounds__(256, 4) void attn_kernel(
    const f16* __restrict__ qb, const f16* __restrict__ kb,
    const f16* __restrict__ vtb, const int* __restrict__ mask,
    float* __restrict__ atten, f16* __restrict__ value_h) {
    __shared__ f16 P[16 * 1048];        // 32.75 KB, stride 1048 -> 2-way banks (free)
    __shared__ float red[2][4][16];     // [max/sum][wave][row]
    const int m0 = blockIdx.x * 16;
    const int h = blockIdx.y, b = blockIdx.z;
    const int bh = b * 16 + h;
    const int tid = threadIdx.x;
    const int lane = tid & 63, w = tid >> 6;
    const int l15 = lane & 15, quad = lane >> 4;

    // phase 1: scores in registers. C layout: row=quad*4+r, col=n0+l15.
    const f16* qbase = qb + (size_t)(bh * 1024 + m0 + l15) * 64 + quad * 8;
    f16x8 a0 = *(const f16x8*)(qbase);
    f16x8 a1 = *(const f16x8*)(qbase + 32);
    f32x4 s[16];
    for (int t = 0; t < 16; ++t) {
        int n0 = w * 256 + t * 16;
        const f16* kbase = kb + (size_t)(bh * 1024 + n0 + l15) * 64 + quad * 8;
        f16x8 b0 = *(const f16x8*)(kbase);
        f16x8 b1 = *(const f16x8*)(kbase + 32);
        f32x4 c = {0.f, 0.f, 0.f, 0.f};
        c = __builtin_amdgcn_mfma_f32_16x16x32_f16(a0, b0, c, 0, 0, 0);
        c = __builtin_amdgcn_mfma_f32_16x16x32_f16(a1, b1, c, 0, 0, 0);
        bool msk = (mask[b * 1024 + n0 + l15] == 0);
        for (int r = 0; r < 4; ++r) s[t][r] = msk ? MIN_VALUE : c[r] * 0.125f;
    }

    // phase 2a: row maxes (lane-local over t, shuffle over l15, LDS over waves)
    float mx[4];
    for (int r = 0; r < 4; ++r) {
        float m = s[0][r];
        for (int t = 1; t < 16; ++t) m = fmaxf(m, s[t][r]);
        for (int o = 1; o < 16; o <<= 1) m = fmaxf(m, __shfl_xor(m, o));
        mx[r] = m;
    }
    if (l15 == 0)
        for (int r = 0; r < 4; ++r) red[0][w][quad * 4 + r] = mx[r];
    __syncthreads();
    for (int r = 0; r < 4; ++r) {
        int row = quad * 4 + r;
        mx[r] = fmaxf(fmaxf(red[0][0][row], red[0][1][row]),
                      fmaxf(red[0][2][row], red[0][3][row]));
    }

    // phase 2b: exp (unnormalized), f16 P to LDS, row sums
    float sum[4] = {0.f, 0.f, 0.f, 0.f};
    for (int t = 0; t < 16; ++t)
        for (int r = 0; r < 4; ++r) {
            float e = __expf(s[t][r] - mx[r]);
            sum[r] += e;
            P[(quad * 4 + r) * 1048 + w * 256 + t * 16 + l15] = (f16)e;
        }
    for (int r = 0; r < 4; ++r) {
        float sm = sum[r];
        for (int o = 1; o < 16; o <<= 1) sm += __shfl_xor(sm, o);
        sum[r] = sm;
    }
    if (l15 == 0)
        for (int r = 0; r < 4; ++r) red[1][w][quad * 4 + r] = sum[r];
    __syncthreads();   // covers P writes AND sum reduction
    float inv[4];
    for (int r = 0; r < 4; ++r) {
        int row = quad * 4 + r;
        inv[r] = 1.0f / (red[1][0][row] + red[1][1][row] +
                         red[1][2][row] + red[1][3][row]);
    }

    // phase 2c: coalesced normalized atten store. Wave w owns rows [w*4, w*4+4):
    // re-read f16 P, scale, write float4 (64 lanes x 16 B = 1 KB contiguous).
    for (int r = 0; r < 4; ++r) {
        int row = w * 4 + r;
        float invr = 1.0f / (red[1][0][row] + red[1][1][row] +
                             red[1][2][row] + red[1][3][row]);
        float* out = atten + (size_t)(bh * 1024 + m0 + row) * 1024;
        for (int e = 0; e < 4; ++e) {
            f16x4 pv = *(const f16x4*)&P[row * 1048 + e * 256 + lane * 4];
            f32x4 o;
            for (int q2 = 0; q2 < 4; ++q2) o[q2] = (float)pv[q2] * invr;
            *(f32x4*)(out + e * 256 + lane * 4) = o;
        }
    }

    // phase 3: value = (P @ v) * inv ; wave w does d-cols [w*16, w*16+16)
    f32x4 acc = {0.f, 0.f, 0.f, 0.f};
    const f16* vbase = vtb + (size_t)(bh * 64 + w * 16 + l15) * 1024 + quad * 8;
    for (int kk = 0; kk < 1024; kk += 32) {
        f16x8 af = *(const f16x8*)&P[l15 * 1048 + kk + quad * 8];
        f16x8 bf_ = *(const f16x8*)(vbase + kk);
        acc = __builtin_amdgcn_mfma_f32_16x16x32_f16(af, bf_, acc, 0, 0, 0);
    }
    for (int r = 0; r < 4; ++r) {
        int mrow = quad * 4 + r;
        value_h[(size_t)(b * 1024 + m0 + mrow) * 1024 + h * 64 + w * 16 + l15] =
            (f16)(acc[r] * inv[r]);
    }
}

// ------------------------------- out-proj GEMM: pre = x + value @ Wo^T + bo  (fp16)
// 128x64 tiles -> 512 blocks = 2 blocks/CU for cross-block latency hiding.
__global__ __launch_bounds__(256) void outproj_kernel(
    const f16* __restrict__ vb, const f16* __restrict__ wob,
    const float* __restrict__ x, const float* __restrict__ bo,
    float* __restrict__ pre) {
    __shared__ f16 As[128 * 32];
    __shared__ f16 Bs[64 * 32];
    const int tid = threadIdx.x;
    const int m0 = blockIdx.y * 128;
    const int n0 = blockIdx.x * 64;
    const int lane = tid & 63, w = tid >> 6;
    const int l15 = lane & 15, quad = lane >> 4;
    const int wm = (w & 1) * 64, wn = (w >> 1) * 32;
    const int r4 = lane >> 2;
    const int c8 = (lane & 3) * 8;

    f32x4 acc[4][2];
    for (int i = 0; i < 4; ++i)
        for (int j = 0; j < 2; ++j)
            for (int r = 0; r < 4; ++r) acc[i][j][r] = 0.0f;

    for (int kk = 0; kk < 1024; kk += 32) {
        __syncthreads();
        for (int half = 0; half < 2; ++half) {
            int row = w * 32 + half * 16 + r4;
            int lo = w * 1024 + half * 512 + lane * 8;
            async_load16(&vb[(size_t)(m0 + row) * 1024 + kk + c8], &As[lo]);
        }
        {
            int row = w * 16 + r4;
            int lo = w * 512 + lane * 8;
            async_load16(&wob[(size_t)(n0 + row) * 1024 + kk + c8], &Bs[lo]);
        }
        __syncthreads();
        f16x8 af[4], bfr[2];
        for (int i = 0; i < 4; ++i) af[i] = *(const f16x8*)&As[(wm + i * 16 + l15) * 32 + quad * 8];
        for (int j = 0; j < 2; ++j) bfr[j] = *(const f16x8*)&Bs[(wn + j * 16 + l15) * 32 + quad * 8];
        for (int i = 0; i < 4; ++i)
            for (int j = 0; j < 2; ++j)
                acc[i][j] = __builtin_amdgcn_mfma_f32_16x16x32_f16(af[i], bfr[j], acc[i][j], 0, 0, 0);
    }

    for (int i = 0; i < 4; ++i)
        for (int j = 0; j < 2; ++j)
            for (int r = 0; r < 4; ++r) {
                int m = m0 + wm + i * 16 + quad * 4 + r;
                int n = n0 + wn + j * 16 + l15;
                pre[(size_t)m * 1024 + n] = acc[i][j][r] + x[(size_t)m * 1024 + n] + bo[n];
            }
}

// ---------------------------------------------------------------- LayerNorm (in place)
__global__ __launch_bounds__(256) void ln_kernel(float* __restrict__ buf,
                                                 const float* __restrict__ gamma,
                                                 const float* __restrict__ beta) {
    const int row = blockIdx.x;
    const int tid = threadIdx.x;
    const int lane = tid & 63, w = tid >> 6;
    __shared__ float red[8];
    float* rp = buf + (size_t)row * 1024;
    float loc[4];
    float s = 0.f, s2 = 0.f;
    for (int e = 0; e < 4; ++e) {
        loc[e] = rp[tid + e * 256];
        s += loc[e];
        s2 += loc[e] * loc[e];
    }
    for (int o = 32; o > 0; o >>= 1) {
        s += __shfl_xor(s, o);
        s2 += __shfl_xor(s2, o);
    }
    if (lane == 0) { red[w * 2] = s; red[w * 2 + 1] = s2; }
    __syncthreads();
    float ts = red[0] + red[2] + red[4] + red[6];
    float ts2 = red[1] + red[3] + red[5] + red[7];
    float mu = ts * (1.0f / 1024.0f);
    float var = ts2 * (1.0f / 1024.0f) - mu * mu;
    float sc = rsqrtf(var + 1e-5f);
    for (int e = 0; e < 4; ++e) {
        int c = tid + e * 256;
        rp[c] = (loc[e] - mu) * sc * gamma[c] + beta[c];
    }
}

extern "C" void kernel_launch(void* const* d_in, const int* in_sizes, int n_in,
                              void* d_out, int out_size, void* d_ws, size_t ws_size,
                              hipStream_t stream) {
    const float* x    = (const float*)d_in[0];
    const int*   mask = (const int*)d_in[1];
    const float* Wq   = (const float*)d_in[2];
    const float* bq   = (const float*)d_in[3];
    const float* Wk   = (const float*)d_in[4];
    const float* bk   = (const float*)d_in[5];
    const float* Wv   = (const float*)d_in[6];
    const float* bv   = (const float*)d_in[7];
    const float* Wo   = (const float*)d_in[8];
    const float* bo   = (const float*)d_in[9];
    const float* gamma= (const float*)d_in[10];
    const float* beta = (const float*)d_in[11];

    char* p = (char*)d_ws;
    f16* xh   = (f16*)p; p += (size_t)4194304 * 2;   // x f16
    f16* wt   = (f16*)p; p += (size_t)3145728 * 2;   // Wqkv^T f16 [3072][1024]
    f16* wob  = (f16*)p; p += (size_t)1048576 * 2;   // Wo f16 [n][k]
    f16* qb   = (f16*)p; p += (size_t)4194304 * 2;   // q [bh][l][64]
    f16* kb   = (f16*)p; p += (size_t)4194304 * 2;   // k [bh][l][64]
    f16* vtb  = (f16*)p; p += (size_t)4194304 * 2;   // v^T [bh][64][1024]
    f16* valb = (f16*)p; p += (size_t)4194304 * 2;   // value [b*l][1024]

    float* outb  = (float*)d_out;            // [4096][1024] : pre, then LN in place
    float* atten = outb + 4194304;           // [64][1024][1024]

    prep_kernel<<<8192, 256, 0, stream>>>(x, Wq, Wk, Wv, Wo, xh, wt, wob);
    qkv_gemm_kernel<<<dim3(24, 32), 256, 0, stream>>>(xh, wt, bq, bk, bv, qb, kb, vtb);
    attn_kernel<<<dim3(64, 16, 4), 256, 0, stream>>>(qb, kb, vtb, mask, atten, valb);
    outproj_kernel<<<dim3(16, 32), 256, 0, stream>>>(valb, wob, x, bo, outb);
    ln_kernel<<<4096, 256, 0, stream>>>(outb, gamma, beta);
}